// Round 12
// baseline (315.127 us; speedup 1.0000x reference)
//
#include <hip/hip_runtime.h>

typedef unsigned int u32;
typedef unsigned char u8;
typedef unsigned long long u64;
typedef int i32x4 __attribute__((ext_vector_type(4)));
typedef int i32x16 __attribute__((ext_vector_type(16)));

// Workspace layout (3.8 MB used):
//   [0, 589824)          Wm[stp=kcL*36+tap*4+kc4][oc][ic32] i8, 8KB per step
//   [589824, +3211264)   bp bitplanes: bp[(n*256+ch)*49 + (px>>6)], bit px&63
#define WM_OFF 0
#define BP_OFF 589824
#define ROWB 7424   // LDS bytes per padded row per phase: 58 w' * 128 ic

// ---------------------------------------------------------------------------
// Kernel 1: prep = pack_w (blocks 0..2303) + bin_bits (blocks 2304..3871).
// pack_w layout [kcL][tap][kc4][oc][ic32]: the conv's 72-step A-walk is
// linear across the kc-split phase boundary.
// ---------------------------------------------------------------------------
__global__ __launch_bounds__(256) void prep(const int* __restrict__ enc,
                                            const float* __restrict__ cb,
                                            char* __restrict__ wm,
                                            const float* __restrict__ x,
                                            u64* __restrict__ bp) {
    int bid = blockIdx.x;
    if (bid < 2304) {
        int idx  = bid * 256 + threadIdx.x;          // 0..589823
        int icin = idx & 31;
        int oc   = (idx >> 5) & 255;
        int stp  = idx >> 13;                        // 0..71
        int kcL  = stp / 36;
        int r36  = stp - kcL * 36;
        int tap  = r36 >> 2;
        int kc4  = r36 & 3;
        int i = kcL * 128 + kc4 * 32 + icin;
        int f = oc * 2304 + i * 9 + tap;             // OIHW flat index
        int j = f / 12;
        int t = f - j * 12;
        float v = cb[enc[j] * 12 + t];
        wm[idx] = v < 0.f ? (char)-1 : (char)1;
    } else {
        int gw   = (bid - 2304) * 4 + (threadIdx.x >> 6);  // 0..6271
        int lane = threadIdx.x & 63;
        const float* xb = x + (size_t)gw * 4096 + lane;
#pragma unroll 1
        for (int k = 0; k < 8; ++k) {
            float v[8];
#pragma unroll
            for (int j = 0; j < 8; ++j) v[j] = xb[k * 512 + j * 64];
            u64 mine = 0;
#pragma unroll
            for (int j = 0; j < 8; ++j) {
                u64 m = __ballot(v[j] < 0.f);
                if (lane == j) mine = m;
            }
            if (lane < 8) bp[(size_t)gw * 64 + k * 8 + lane] = mine;
        }
    }
}

// ---------------------------------------------------------------------------
// Expand one padded row x 128 channels (one kc-phase) into the swizzled LDS
// tile. thread (oct16, wseg): channels chb+oct16*8..+8, w' = wseg+4k.
// 16 bp loads (L2-hot), <=15 u64 LDS writes at [wq*128 + (oct*8 ^ key(wq))].
// ---------------------------------------------------------------------------
__device__ __forceinline__ void expand_row(const u64* __restrict__ bp, u8* xr,
                                           int chb, int h, int oct16, int wseg) {
    bool rowv = (h >= 0) && (h <= 55);
    int w0c = rowv ? ((h * 56) >> 6) : 0;
    int w1c = w0c + 1; if (w1c > 48) w1c = 48;
    const u64* bq = bp + ((size_t)(chb + oct16 * 8)) * 49;
    u64 A[8], B[8];
#pragma unroll
    for (int j = 0; j < 8; ++j) A[j] = bq[j * 49 + w0c];
#pragma unroll
    for (int j = 0; j < 8; ++j) B[j] = bq[j * 49 + w1c];
#pragma unroll 1
    for (int k = 0; k < 15; ++k) {
        int wq = wseg + k * 4;
        if (wq >= 58) break;
        u64 out = 0;
        if (rowv && wq >= 1 && wq <= 56) {
            int px  = h * 56 + wq - 1;
            int bit = px & 63;
            bool s2 = (px >> 6) != w0c;
#pragma unroll
            for (int j = 0; j < 8; ++j) {
                u64 wv = s2 ? B[j] : A[j];
                out |= (((wv >> bit) & 1ull) ? 0xFFull : 0x01ull) << (8 * j);
            }
        }
        *(u64*)(xr + wq * 128 + ((oct16 * 8) ^ ((wq & 7) << 4))) = out;
    }
}

// ---------------------------------------------------------------------------
// Kernel 2: i8 MFMA conv (R12). 256 thr, 4 waves = 256 oc x 64 px = ONE
// output row; ic SPLIT into 2 phases of 128 channels.
// R11 post-mortem: s_sleep null -> not lockstep; occupancy (31%) is the wall:
// R10's 62KB LDS capped 2 blocks/CU and grid 896/256=3.5 left long 1-block
// tails. R12: LDS/phase = 3 rows x 58 x 128 = 21.8KB (alloc 23KB w/ slack),
// grid 1792 = 7 blocks/CU queue, ~4 resident (reg cap 120/wave -> 16
// waves/CU). Inner pipeline IDENTICAL to R9/R10 (no-spill proven): period-2
// Ae/Ao + Be/Bo ping-pong, zero movs, REGION = 4 steps (kc4 0..3).
// Phase loop: [barrier; expand 128ch; barrier; 9 taps x REGION].
// Swizzle key (w'&7)<<4 (128-ic range): B-reads 4-way conflict (1.58x, minor).
// C/D: col=l&31 (px), row=(q&3)+8*(q>>2)+4*(l>>5) (oc)  [HW-verified].
// ---------------------------------------------------------------------------
__global__ __launch_bounds__(256, 4) void conv_mfma(const u64* __restrict__ bp,
                                                    const char* __restrict__ wm,
                                                    float* __restrict__ y) {
    __shared__ __align__(16) u8 xl[23552];   // 3*7424=22272 + dead-read slack
    int t = threadIdx.x;
    // XCD-aware bijective remap (1792 % 8 == 0): 224 consecutive tiles/XCD.
    int lin = blockIdx.x + 56 * blockIdx.y;
    int swb = (lin & 7) * 224 + (lin >> 3);
    int n   = swb / 56;
    int h   = swb - n * 56;                  // output row 0..55

    int oct = t & 15, wseg = (t >> 4) & 3, rr = t >> 6;   // rr == wave
    int wave = t >> 6, lane = t & 63;
    int col  = lane & 31;
    int half = lane >> 5;
    int ocw  = wave * 64;
    int aoff = (ocw + col) * 32 + half * 16;
    int h16  = half * 16;

    // Prime A even-slot with step 0 (global, no LDS dep -> hides under the
    // first expansion + barrier).
    const char* wb = wm;
    i32x4 Aea = *(const i32x4*)(wb + aoff);
    i32x4 Aeb = *(const i32x4*)(wb + aoff + 1024);
    wb += 8192;                               // -> step 1

    int swA = ((col + 0) & 7) << 4, cbA = (col + 0) * 128;
    int swB = ((col + 1) & 7) << 4, cbB = (col + 1) * 128;
    int swC = ((col + 2) & 7) << 4, cbC = (col + 2) * 128;

    i32x16 acc[2][2] = {};
    i32x4 Aoa, Aob, Be0, Be1, Bo0, Bo1;

#define MFMA4(AA, AB, B0, B1)                                                  \
    acc[0][0] = __builtin_amdgcn_mfma_i32_32x32x32_i8(AA, B0, acc[0][0], 0, 0, 0); \
    acc[0][1] = __builtin_amdgcn_mfma_i32_32x32x32_i8(AA, B1, acc[0][1], 0, 0, 0); \
    acc[1][0] = __builtin_amdgcn_mfma_i32_32x32x32_i8(AB, B0, acc[1][0], 0, 0, 0); \
    acc[1][1] = __builtin_amdgcn_mfma_i32_32x32x32_i8(AB, B1, acc[1][1], 0, 0, 0);

// One region = one (kcL, tap): 4 K-steps as 2 unroll-1 iterations of 2 steps.
// b1 tile = w'+32 = +4096 bytes, same swizzle key ((w'+32)&7 == w'&7).
// kc2=1's even prefetch is dead (reads <= base+255+4096, in-bounds slack).
#define REGION(CBASE, SWV)                                                     \
    {                                                                          \
        const int _bb = (CBASE);                                               \
        {                                                                      \
            int _p = _bb + (h16 ^ (SWV));                                      \
            Be0 = *(const i32x4*)&xl[_p];                                      \
            Be1 = *(const i32x4*)&xl[_p + 4096];                               \
        }                                                                      \
        _Pragma("unroll 1")                                                    \
        for (int kc2 = 0; kc2 < 2; ++kc2) {                                    \
            int _kb = kc2 * 64;                                                \
            int _ko = _bb + ((_kb + 32 + h16) ^ (SWV));                        \
            Bo0 = *(const i32x4*)&xl[_ko];                                     \
            Bo1 = *(const i32x4*)&xl[_ko + 4096];                              \
            Aoa = *(const i32x4*)(wb + aoff);                                  \
            Aob = *(const i32x4*)(wb + aoff + 1024);                           \
            wb += 8192;                                                        \
            MFMA4(Aea, Aeb, Be0, Be1)                                          \
            int _ke = _bb + ((_kb + 64 + h16) ^ (SWV));                        \
            Be0 = *(const i32x4*)&xl[_ke];                                     \
            Be1 = *(const i32x4*)&xl[_ke + 4096];                              \
            Aea = *(const i32x4*)(wb + aoff);                                  \
            Aeb = *(const i32x4*)(wb + aoff + 1024);                           \
            wb += 8192;                                                        \
            MFMA4(Aoa, Aob, Bo0, Bo1)                                          \
        }                                                                      \
    }

#pragma unroll 1
    for (int kcL = 0; kcL < 2; ++kcL) {
        if (kcL) __syncthreads();            // phase-0 reads complete
        if (rr < 3)
            expand_row(bp, xl + rr * ROWB, n * 256 + kcL * 128,
                       h + rr - 1, oct, wseg);
        __syncthreads();
#pragma unroll 1
        for (int r = 0; r < 3; ++r) {
            int rowb = r * ROWB;
            REGION(rowb + cbA, swA)
            REGION(rowb + cbB, swB)
            REGION(rowb + cbC, swC)
        }
    }
#undef REGION
#undef MFMA4

    // Final Ae prefetch walked to step 72 (8KB into bp region): dead, valid.
    float* yb = y + (size_t)n * 256 * 3136 + (size_t)h * 56;
#pragma unroll
    for (int at = 0; at < 2; ++at) {
#pragma unroll
        for (int bt = 0; bt < 2; ++bt) {
            int w = bt * 32 + col;
            if (w < 56) {
#pragma unroll
                for (int q = 0; q < 16; ++q) {
                    int oc = ocw + at * 32 + (q & 3) + 8 * (q >> 2) + 4 * half;
                    yb[(size_t)oc * 3136 + w] = (float)acc[at][bt][q];
                }
            }
        }
    }
}

extern "C" void kernel_launch(void* const* d_in, const int* in_sizes, int n_in,
                              void* d_out, int out_size, void* d_ws, size_t ws_size,
                              hipStream_t stream) {
    const float* x  = (const float*)d_in[0];
    // d_in[1] (latent weight) unused in the STE forward value.
    const float* cb = (const float*)d_in[2];
    const int* enc  = (const int*)d_in[3];
    float* y        = (float*)d_out;

    char* wmc = (char*)d_ws + WM_OFF;
    u64*  bp  = (u64*)((char*)d_ws + BP_OFF);

    hipLaunchKernelGGL(prep, dim3(3872), dim3(256), 0, stream, enc, cb, wmc, x, bp);
    hipLaunchKernelGGL(conv_mfma, dim3(56, 32), dim3(256), 0, stream, bp, wmc, y);
}

// Round 13
// 239.809 us; speedup vs baseline: 1.3141x; 1.3141x over previous
//
#include <hip/hip_runtime.h>

typedef unsigned int u32;
typedef unsigned char u8;
typedef unsigned long long u64;
typedef int i32x4 __attribute__((ext_vector_type(4)));
typedef int i32x8 __attribute__((ext_vector_type(8)));
typedef float f32x16 __attribute__((ext_vector_type(16)));

// Workspace layout (3.8 MB used):
//   [0, 294912)          Wm fp4: [stp=tap*4+k64][oc][32B] (64 ic nibbles/oc),
//                        8KB per step; nibble 0x2=+1, 0xA=-1 (e2m1), low
//                        nibble = even ic.
//   [589824, +3211264)   bp bitplanes: bp[(n*256+ch)*49 + (px>>6)], bit px&63
#define WM_OFF 0
#define BP_OFF 589824
#define ROWB 7424   // LDS bytes per padded row: 58 w' * 128B (256 ic nibbles)

// ---------------------------------------------------------------------------
// Kernel 1: prep = pack_w fp4 (blocks 0..287) + bin_bits (blocks 288..1855).
// pack_w: thread = one u32 (8 ic nibbles) of Wm. 8 codebook gathers (L2-hot).
// ---------------------------------------------------------------------------
__global__ __launch_bounds__(256) void prep(const int* __restrict__ enc,
                                            const float* __restrict__ cb,
                                            u32* __restrict__ wm,
                                            const float* __restrict__ x,
                                            u64* __restrict__ bp) {
    int bid = blockIdx.x;
    if (bid < 288) {
        int idx = bid * 256 + threadIdx.x;           // 0..73727 u32 words
        int g   = idx & 7;                           // 8B group within 32B row
        int oc  = (idx >> 3) & 255;
        int stp = idx >> 11;                         // 0..35 = tap*4 + k64
        int tap = stp >> 2;
        int k64 = stp & 3;
        u32 word = 0;
#pragma unroll
        for (int e = 0; e < 8; ++e) {
            int i = k64 * 64 + g * 8 + e;            // ic
            int f = oc * 2304 + i * 9 + tap;         // OIHW flat index
            int j = f / 12;
            int t = f - j * 12;
            float v = cb[enc[j] * 12 + t];
            word |= (v < 0.f ? 0xAu : 0x2u) << (4 * e);
        }
        wm[idx] = word;
    } else {
        int gw   = (bid - 288) * 4 + (threadIdx.x >> 6);   // 0..6271
        int lane = threadIdx.x & 63;
        const float* xb = x + (size_t)gw * 4096 + lane;
#pragma unroll 1
        for (int k = 0; k < 8; ++k) {
            float v[8];
#pragma unroll
            for (int j = 0; j < 8; ++j) v[j] = xb[k * 512 + j * 64];
            u64 mine = 0;
#pragma unroll
            for (int j = 0; j < 8; ++j) {
                u64 m = __ballot(v[j] < 0.f);
                if (lane == j) mine = m;
            }
            if (lane < 8) bp[(size_t)gw * 64 + k * 8 + lane] = mine;
        }
    }
}

// ---------------------------------------------------------------------------
// Expand one padded row of bitplanes -> fp4 nibbles in swizzled LDS.
// thread (oct, wseg): channels oct*8..+8 (8 nibbles = u32), w' = wseg+4k.
// Halo -> 0x0 nibbles (+0.0 contributes 0, replaces i8's 0x00 byte).
// Write addr: wq*128 + ((oct*4) ^ ((wq&7)<<4)) — conflict-free (32 banks).
// ---------------------------------------------------------------------------
__device__ __forceinline__ void expand_row(const u64* __restrict__ bp, u8* xr,
                                           int n, int h, int oct, int wseg) {
    bool rowv = (h >= 0) && (h <= 55);
    int w0c = rowv ? ((h * 56) >> 6) : 0;
    int w1c = w0c + 1; if (w1c > 48) w1c = 48;
    const u64* bq = bp + ((size_t)n * 256 + oct * 8) * 49;
    u64 A[8], B[8];
#pragma unroll
    for (int j = 0; j < 8; ++j) A[j] = bq[j * 49 + w0c];
#pragma unroll
    for (int j = 0; j < 8; ++j) B[j] = bq[j * 49 + w1c];
#pragma unroll 1
    for (int k = 0; k < 15; ++k) {
        int wq = wseg + k * 4;
        if (wq >= 58) break;
        u32 out = 0;
        if (rowv && wq >= 1 && wq <= 56) {
            int px  = h * 56 + wq - 1;
            int bit = px & 63;
            bool s2 = (px >> 6) != w0c;
#pragma unroll
            for (int j = 0; j < 8; ++j) {
                u64 wv = s2 ? B[j] : A[j];
                out |= (((wv >> bit) & 1ull) ? 0xAu : 0x2u) << (4 * j);
            }
        }
        *(u32*)(xr + wq * 128 + ((oct * 4) ^ ((wq & 7) << 4))) = out;
    }
}

// ---------------------------------------------------------------------------
// Kernel 2: MX-FP4 MFMA conv (R13 = R10 skeleton, dtype i8 -> fp4).
// 512 thr, 8 waves = 256 oc x 128 px (2 output rows). 36 K-steps of K=64
// (9 taps x 4), 4 x mfma_scale_f32_32x32x64_f8f6f4 (fmt 4 = e2m1, scale
// 0x7F = x1.0) per step. Same zero-mov period-2 Ae/Ao + Be/Bo ping-pong as
// R10 (no-spill proven). A/B both use ic = k64*64 + half*32 + e (identical
// maps -> HW k-permutation cancels); C/D layout shape-determined (verified).
// acc is f32 -> epilogue stores directly (64 v_cvt eliminated).
// B-reads: 4-way bank conflict (128B-row swizzle limit), 1.58x on a halved
// LDS pipe -> net win. A-loads 16B/lane/step, L1 traffic halved.
// C/D: col=l&31 (px), row=(q&3)+8*(q>>2)+4*(l>>5) (oc)  [HW-verified].
// ---------------------------------------------------------------------------
__global__ __launch_bounds__(512, 4) void conv_mfma(const u64* __restrict__ bp,
                                                    const char* __restrict__ wm,
                                                    float* __restrict__ y) {
    __shared__ __align__(16) u8 xl[31744];   // 4*7424=29696 + dead-read slack
    int t = threadIdx.x;
    // XCD-aware bijective remap (896 % 8 == 0): 4 consecutive n per XCD.
    int lin = blockIdx.x + 28 * blockIdx.y;
    int swb = (lin & 7) * 112 + (lin >> 3);
    int n   = swb / 28;
    int h0  = (swb - n * 28) * 2;

    int oct = t & 31, wseg = (t >> 5) & 3, rr = t >> 7;
    int wave = t >> 6, lane = t & 63;
    int ocg  = wave & 3;
    int pxg  = wave >> 2;
    int col  = lane & 31;
    int half = lane >> 5;
    int ocw  = ocg * 64;
    int aoff = (ocw + col) * 32 + half * 16;
    int h16  = half * 16;

    // Prime A even-slot with step 0 (global, no LDS dep -> hides under the
    // expansion + barrier).
    const char* wb = wm;
    i32x4 Aea = *(const i32x4*)(wb + aoff);
    i32x4 Aeb = *(const i32x4*)(wb + aoff + 1024);
    wb += 8192;                               // -> step 1

    expand_row(bp, xl + rr * ROWB, n, h0 + rr - 1, oct, wseg);
    __syncthreads();

    int swA = ((col + 0) & 7) << 4, cbA = (col + 0) * 128;
    int swB = ((col + 1) & 7) << 4, cbB = (col + 1) * 128;
    int swC = ((col + 2) & 7) << 4, cbC = (col + 2) * 128;
    int pxb = pxg * ROWB;

    f32x16 acc[2][2] = {};
    i32x4 Aoa, Aob, Be0, Be1, Bo0, Bo1;

#define UP8(V) (i32x8){(V)[0], (V)[1], (V)[2], (V)[3], 0, 0, 0, 0}
#define MFMA4(AA, AB, B0, B1)                                                  \
    acc[0][0] = __builtin_amdgcn_mfma_scale_f32_32x32x64_f8f6f4(               \
        UP8(AA), UP8(B0), acc[0][0], 4, 4, 0, 0x7F7F7F7F, 0, 0x7F7F7F7F);      \
    acc[0][1] = __builtin_amdgcn_mfma_scale_f32_32x32x64_f8f6f4(               \
        UP8(AA), UP8(B1), acc[0][1], 4, 4, 0, 0x7F7F7F7F, 0, 0x7F7F7F7F);      \
    acc[1][0] = __builtin_amdgcn_mfma_scale_f32_32x32x64_f8f6f4(               \
        UP8(AB), UP8(B0), acc[1][0], 4, 4, 0, 0x7F7F7F7F, 0, 0x7F7F7F7F);      \
    acc[1][1] = __builtin_amdgcn_mfma_scale_f32_32x32x64_f8f6f4(               \
        UP8(AB), UP8(B1), acc[1][1], 4, 4, 0, 0x7F7F7F7F, 0, 0x7F7F7F7F);

// One region = one tap: 4 K64-steps as 2 unroll-1 iterations of 2 steps.
// Second px tile = w'+32 -> +4096B, same swizzle key ((w'+32)&7 == w'&7).
// kc2=1's even prefetch (byte 128+) is dead: reads next w' row, harmless.
#define REGION(CBASE, SWV)                                                     \
    {                                                                          \
        const int _bb = (CBASE);                                               \
        {                                                                      \
            int _p = _bb + (h16 ^ (SWV));                                      \
            Be0 = *(const i32x4*)&xl[_p];                                      \
            Be1 = *(const i32x4*)&xl[_p + 4096];                               \
        }                                                                      \
        _Pragma("unroll 1")                                                    \
        for (int kc2 = 0; kc2 < 2; ++kc2) {                                    \
            int _kb = kc2 * 64;                                                \
            int _ko = _bb + ((_kb + 32 + h16) ^ (SWV));                        \
            Bo0 = *(const i32x4*)&xl[_ko];                                     \
            Bo1 = *(const i32x4*)&xl[_ko + 4096];                              \
            Aoa = *(const i32x4*)(wb + aoff);                                  \
            Aob = *(const i32x4*)(wb + aoff + 1024);                           \
            wb += 8192;                                                        \
            MFMA4(Aea, Aeb, Be0, Be1)                                          \
            int _ke = _bb + ((_kb + 64 + h16) ^ (SWV));                        \
            Be0 = *(const i32x4*)&xl[_ke];                                     \
            Be1 = *(const i32x4*)&xl[_ke + 4096];                              \
            Aea = *(const i32x4*)(wb + aoff);                                  \
            Aeb = *(const i32x4*)(wb + aoff + 1024);                           \
            wb += 8192;                                                        \
            MFMA4(Aoa, Aob, Bo0, Bo1)                                          \
        }                                                                      \
    }

#pragma unroll 1
    for (int r = 0; r < 3; ++r) {
        int rowb = pxb + r * ROWB;
        REGION(rowb + cbA, swA)
        REGION(rowb + cbB, swB)
        REGION(rowb + cbC, swC)
    }
#undef REGION
#undef MFMA4
#undef UP8

    // Final Ae prefetch walked to step 37 (within ws gap below bp): dead, ok.
    int h = h0 + pxg;
    float* yb = y + (size_t)n * 256 * 3136 + (size_t)h * 56;
#pragma unroll
    for (int at = 0; at < 2; ++at) {
#pragma unroll
        for (int bt = 0; bt < 2; ++bt) {
            int w = bt * 32 + col;
            if (w < 56) {
#pragma unroll
                for (int q = 0; q < 16; ++q) {
                    int oc = ocw + at * 32 + (q & 3) + 8 * (q >> 2) + 4 * half;
                    yb[(size_t)oc * 3136 + w] = acc[at][bt][q];
                }
            }
        }
    }
}

extern "C" void kernel_launch(void* const* d_in, const int* in_sizes, int n_in,
                              void* d_out, int out_size, void* d_ws, size_t ws_size,
                              hipStream_t stream) {
    const float* x  = (const float*)d_in[0];
    // d_in[1] (latent weight) unused in the STE forward value.
    const float* cb = (const float*)d_in[2];
    const int* enc  = (const int*)d_in[3];
    float* y        = (float*)d_out;

    u32*  wmc = (u32*)((char*)d_ws + WM_OFF);
    u64*  bp  = (u64*)((char*)d_ws + BP_OFF);

    hipLaunchKernelGGL(prep, dim3(1856), dim3(256), 0, stream, enc, cb, wmc, x, bp);
    hipLaunchKernelGGL(conv_mfma, dim3(28, 32), dim3(512), 0, stream, bp,
                       (const char*)wmc, y);
}